// Round 2
// baseline (900.176 us; speedup 1.0000x reference)
//
#include <hip/hip_runtime.h>

#define Nn 100000
#define Ee 1600000
#define Ff 128
#define Gg 512
#define Cc 40
#define NCH 2048
#define CH  49   // ceil(Nn / NCH)

// ---------------- BN/bias folding: sc/sh per layer-feature ----------------
__global__ void prep_scales_k(const float* __restrict__ conv_b,
                              const float* __restrict__ gamma,
                              const float* __restrict__ beta,
                              const float* __restrict__ mean,
                              const float* __restrict__ var,
                              float* __restrict__ sc, float* __restrict__ sh)
{
    int i = blockIdx.x * blockDim.x + threadIdx.x;
    if (i >= 3 * Ff) return;
    float b = conv_b[i];
    if (i < 2 * Ff) {  // layers 0,1 have BN
        float s = gamma[i] * rsqrtf(var[i] + 1e-5f);
        sc[i] = s;
        sh[i] = (b - mean[i]) * s + beta[i];
    } else {           // layer 2: no BN
        sc[i] = 1.0f;
        sh[i] = b;
    }
}

// ---------------- CSR build ----------------
__global__ void count_edges_k(const int* __restrict__ dst, int* __restrict__ deg)
{
    int e = blockIdx.x * 256 + threadIdx.x;
    if (e < Ee) atomicAdd(&deg[dst[e]], 1);
}

__global__ void chunk_sum_k(const int* __restrict__ deg, int* __restrict__ csum)
{
    int t = blockIdx.x * 256 + threadIdx.x;
    if (t >= NCH) return;
    int i0 = t * CH, i1 = min(i0 + CH, Nn);
    int s = 0;
    for (int i = i0; i < i1; ++i) s += deg[i];
    csum[t] = s;
}

__global__ void scan_chunks_k(const int* __restrict__ csum, int* __restrict__ coff)
{
    __shared__ int tot[256];
    int t = threadIdx.x;
    int v[8]; int s = 0;
    #pragma unroll
    for (int j = 0; j < 8; ++j) { v[j] = csum[t * 8 + j]; s += v[j]; }
    tot[t] = s;
    __syncthreads();
    for (int d = 1; d < 256; d <<= 1) {
        int x = (t >= d) ? tot[t - d] : 0;
        __syncthreads();
        tot[t] += x;
        __syncthreads();
    }
    int base = tot[t] - s;  // exclusive prefix
    #pragma unroll
    for (int j = 0; j < 8; ++j) { coff[t * 8 + j] = base; base += v[j]; }
}

__global__ void write_offsets_k(const int* __restrict__ deg, const int* __restrict__ coff,
                                int* __restrict__ off, float* __restrict__ dinv)
{
    int t = blockIdx.x * 256 + threadIdx.x;
    if (t >= NCH) return;
    int i0 = t * CH, i1 = min(i0 + CH, Nn);
    int run = coff[t];
    for (int i = i0; i < i1; ++i) {
        off[i] = run;
        int d = deg[i];
        run += d;
        dinv[i] = rsqrtf((float)d + 1.0f);  // +1 self loop
    }
    if (t == 0) off[Nn] = Ee;
}

__global__ void fill_csr_k(const int* __restrict__ src, const int* __restrict__ dst,
                           const int* __restrict__ off, int* __restrict__ cur,
                           int* __restrict__ csrc)
{
    int e = blockIdx.x * 256 + threadIdx.x;
    if (e < Ee) {
        int d = dst[e];
        int p = off[d] + atomicAdd(&cur[d], 1);
        csrc[p] = src[e];
    }
}

// ---------------- GEMM: Y[r] = (A[r] @ W) * dinv[r] ----------------
// 128-row tile, W (64KB) + swizzled A-tile (64KB) in LDS. 512 threads:
// 32 rowgroups x 4 rows, 16 colgroups x 8 cols.
// A-tile swizzle: (r,k) stored at As[r*128 + (k ^ (r>>2))] -> the 32-lane
// column read (stride 512B) lands on 32 distinct banks (conflict-free).
__global__ __launch_bounds__(512) void gemm_scale_k(
    const float* __restrict__ A, const float* __restrict__ W,
    const float* __restrict__ dinv, float* __restrict__ Y, int n)
{
    __shared__ float Ws[Ff * Ff];
    __shared__ float As[Ff * Ff];
    const int tid = threadIdx.x;
    const int base = blockIdx.x * 128;

    {   // load W: 16384 floats = 512 thr x 8 float4
        const float4* Wv = (const float4*)W;
        float4* Wsv = (float4*)Ws;
        #pragma unroll
        for (int i = 0; i < 8; ++i) Wsv[tid + i * 512] = Wv[tid + i * 512];
    }
    {   // load A tile (zero-pad OOB rows), swizzled scalar stores
        #pragma unroll
        for (int i = 0; i < 8; ++i) {
            int idx = tid + i * 512;        // 0..4095 float4 slots
            int r   = idx >> 5;             // 32 float4 per row
            int c4  = (idx & 31) << 2;
            int gr  = base + r;
            float4 v = make_float4(0.f, 0.f, 0.f, 0.f);
            if (gr < n) v = *(const float4*)(A + (size_t)gr * Ff + c4);
            int s = (r >> 2) & 31;
            As[r * Ff + ((c4 + 0) ^ s)] = v.x;
            As[r * Ff + ((c4 + 1) ^ s)] = v.y;
            As[r * Ff + ((c4 + 2) ^ s)] = v.z;
            As[r * Ff + ((c4 + 3) ^ s)] = v.w;
        }
    }
    __syncthreads();

    const int rg = tid & 31;   // rows rg*4 .. rg*4+3
    const int cg = tid >> 5;   // cols cg*8 .. cg*8+7
    float acc[4][8];
    #pragma unroll
    for (int a = 0; a < 4; ++a)
        #pragma unroll
        for (int b = 0; b < 8; ++b) acc[a][b] = 0.f;

    const float* pA0 = As + (rg * 4 + 0) * Ff;
    const float* pA1 = As + (rg * 4 + 1) * Ff;
    const float* pA2 = As + (rg * 4 + 2) * Ff;
    const float* pA3 = As + (rg * 4 + 3) * Ff;
    const float4* pW = ((const float4*)Ws) + (cg << 1);

    #pragma unroll 4
    for (int k = 0; k < 128; ++k) {
        const int kx = k ^ rg;
        const float a0 = pA0[kx], a1 = pA1[kx], a2 = pA2[kx], a3 = pA3[kx];
        const float4 w0 = pW[k * 32];
        const float4 w1 = pW[k * 32 + 1];
        const float wv[8] = {w0.x, w0.y, w0.z, w0.w, w1.x, w1.y, w1.z, w1.w};
        #pragma unroll
        for (int j = 0; j < 8; ++j) {
            acc[0][j] += a0 * wv[j];
            acc[1][j] += a1 * wv[j];
            acc[2][j] += a2 * wv[j];
            acc[3][j] += a3 * wv[j];
        }
    }

    #pragma unroll
    for (int jr = 0; jr < 4; ++jr) {
        int gr = base + rg * 4 + jr;
        if (gr < n) {
            float di = dinv[gr];
            float4 o0 = make_float4(acc[jr][0] * di, acc[jr][1] * di,
                                    acc[jr][2] * di, acc[jr][3] * di);
            float4 o1 = make_float4(acc[jr][4] * di, acc[jr][5] * di,
                                    acc[jr][6] * di, acc[jr][7] * di);
            *(float4*)(Y + (size_t)gr * Ff + cg * 8)     = o0;
            *(float4*)(Y + (size_t)gr * Ff + cg * 8 + 4) = o1;
        }
    }
}

// ---------------- aggregation: one wave per node ----------------
// H[i] = act( dinv[i] * (sum_{e in in(i)} Y[src_e] + Y[i]) * sc + sh )
__global__ __launch_bounds__(256) void aggregate_k(
    const float* __restrict__ Y, const int* __restrict__ off,
    const int* __restrict__ srcs, const float* __restrict__ dinv,
    const float* __restrict__ sc, const float* __restrict__ sh,
    float* __restrict__ H, int dorelu, int n)
{
    int wid  = threadIdx.x >> 6;
    int lane = threadIdx.x & 63;
    int node = blockIdx.x * 4 + wid;
    if (node >= n) return;
    int beg = off[node], end = off[node + 1];
    int c = lane * 2;

    float2 self = *(const float2*)(Y + (size_t)node * Ff + c);
    float ax = self.x, ay = self.y;   // acc pair A
    float bx = 0.f,    by = 0.f;      // acc pair B (break dep chain)

    for (int e = beg; e < end; e += 64) {
        int nb = min(64, end - e);
        int sidx = (lane < nb) ? srcs[e + lane] : 0;
        int j = 0;
        for (; j + 4 <= nb; j += 4) {
            int s0 = __shfl(sidx, j);
            int s1 = __shfl(sidx, j + 1);
            int s2 = __shfl(sidx, j + 2);
            int s3 = __shfl(sidx, j + 3);
            float2 v0 = *(const float2*)(Y + (size_t)s0 * Ff + c);
            float2 v1 = *(const float2*)(Y + (size_t)s1 * Ff + c);
            float2 v2 = *(const float2*)(Y + (size_t)s2 * Ff + c);
            float2 v3 = *(const float2*)(Y + (size_t)s3 * Ff + c);
            ax += v0.x; ay += v0.y; bx += v1.x; by += v1.y;
            ax += v2.x; ay += v2.y; bx += v3.x; by += v3.y;
        }
        for (; j < nb; ++j) {
            int s0 = __shfl(sidx, j);
            float2 v0 = *(const float2*)(Y + (size_t)s0 * Ff + c);
            ax += v0.x; ay += v0.y;
        }
    }
    float di = dinv[node];
    float2 scv = *(const float2*)(sc + c);
    float2 shv = *(const float2*)(sh + c);
    float ox = (ax + bx) * di * scv.x + shv.x;
    float oy = (ay + by) * di * scv.y + shv.y;
    if (dorelu) { ox = fmaxf(ox, 0.f); oy = fmaxf(oy, 0.f); }
    *(float2*)(H + (size_t)node * Ff + c) = make_float2(ox, oy);
}

// ---------------- mean-pool (batch sorted -> binary search) + linear ----------------
__global__ __launch_bounds__(128) void pool_linear_k(
    const float* __restrict__ H, const int* __restrict__ batch,
    const float* __restrict__ lw, const float* __restrict__ lb,
    float* __restrict__ out)
{
    int g = blockIdx.x, f = threadIdx.x;
    int lo = 0, hi = Nn;
    while (lo < hi) { int m = (lo + hi) >> 1; if (batch[m] < g) lo = m + 1; else hi = m; }
    int start = lo;
    hi = Nn;
    while (lo < hi) { int m = (lo + hi) >> 1; if (batch[m] < g + 1) lo = m + 1; else hi = m; }
    int end = lo;

    float a0 = 0.f, a1 = 0.f, a2 = 0.f, a3 = 0.f;
    int i = start;
    for (; i + 4 <= end; i += 4) {
        a0 += H[(size_t)(i + 0) * Ff + f];
        a1 += H[(size_t)(i + 1) * Ff + f];
        a2 += H[(size_t)(i + 2) * Ff + f];
        a3 += H[(size_t)(i + 3) * Ff + f];
    }
    for (; i < end; ++i) a0 += H[(size_t)i * Ff + f];
    int cnt = end - start;
    __shared__ float pooled[Ff];
    pooled[f] = ((a0 + a1) + (a2 + a3)) / (float)max(cnt, 1);
    __syncthreads();
    if (f < Cc) {
        float o = lb[f];
        #pragma unroll 8
        for (int k = 0; k < Ff; ++k) o += pooled[k] * lw[k * Cc + f];
        out[g * Cc + f] = o;
    }
}

// ---------------- launch ----------------
extern "C" void kernel_launch(void* const* d_in, const int* in_sizes, int n_in,
                              void* d_out, int out_size, void* d_ws, size_t ws_size,
                              hipStream_t stream)
{
    const float* x      = (const float*)d_in[0];
    const int*   ei     = (const int*)d_in[1];   // [2,E]: src=ei[0:E), dst=ei[E:2E)
    const int*   batch  = (const int*)d_in[2];
    const float* conv_w = (const float*)d_in[3]; // [3,128,128]
    const float* conv_b = (const float*)d_in[4];
    const float* gamma  = (const float*)d_in[5];
    const float* beta   = (const float*)d_in[6];
    const float* mean   = (const float*)d_in[7];
    const float* var    = (const float*)d_in[8];
    const float* lw     = (const float*)d_in[9];
    const float* lb     = (const float*)d_in[10];
    float* out = (float*)d_out;

    const int* srcp = ei;
    const int* dstp = ei + Ee;

    // workspace layout
    float* h    = (float*)d_ws;            // N*F
    float* y    = h + (size_t)Nn * Ff;     // N*F
    float* dinv = y + (size_t)Nn * Ff;     // N
    float* sc   = dinv + Nn;               // 3*F
    float* sh   = sc + 3 * Ff;             // 3*F
    int*   deg  = (int*)(sh + 3 * Ff);     // N
    int*   cur  = deg + Nn;                // N  (adjacent to deg: one memset)
    int*   off  = cur + Nn;                // N+1
    int*   csrc = off + (Nn + 1);          // E
    int*   csum = csrc + Ee;               // NCH
    int*   coff = csum + NCH;              // NCH

    hipMemsetAsync(deg, 0, 2 * (size_t)Nn * sizeof(int), stream);

    prep_scales_k<<<2, 256, 0, stream>>>(conv_b, gamma, beta, mean, var, sc, sh);
    count_edges_k<<<Ee / 256, 256, 0, stream>>>(dstp, deg);
    chunk_sum_k<<<NCH / 256, 256, 0, stream>>>(deg, csum);
    scan_chunks_k<<<1, 256, 0, stream>>>(csum, coff);
    write_offsets_k<<<NCH / 256, 256, 0, stream>>>(deg, coff, off, dinv);
    fill_csr_k<<<Ee / 256, 256, 0, stream>>>(srcp, dstp, off, cur, csrc);

    const int gemm_grid = (Nn + 127) / 128;
    const int agg_grid  = (Nn + 3) / 4;
    for (int l = 0; l < 3; ++l) {
        const float* in = (l == 0) ? x : h;
        gemm_scale_k<<<gemm_grid, 512, 0, stream>>>(in, conv_w + (size_t)l * Ff * Ff,
                                                    dinv, y, Nn);
        aggregate_k<<<agg_grid, 256, 0, stream>>>(y, off, csrc, dinv,
                                                  sc + l * Ff, sh + l * Ff,
                                                  h, (l < 2) ? 1 : 0, Nn);
    }
    pool_linear_k<<<Gg, 128, 0, stream>>>(h, batch, lw, lb, out);
}

// Round 3
// 858.723 us; speedup vs baseline: 1.0483x; 1.0483x over previous
//
#include <hip/hip_runtime.h>

#define Nn 100000
#define Ee 1600000
#define Ff 128
#define Gg 512
#define Cc 40
#define NCH 2048
#define CH  49   // ceil(Nn / NCH)

// ---------------- BN/bias folding: sc/sh per layer-feature ----------------
__global__ void prep_scales_k(const float* __restrict__ conv_b,
                              const float* __restrict__ gamma,
                              const float* __restrict__ beta,
                              const float* __restrict__ mean,
                              const float* __restrict__ var,
                              float* __restrict__ sc, float* __restrict__ sh)
{
    int i = blockIdx.x * blockDim.x + threadIdx.x;
    if (i >= 3 * Ff) return;
    float b = conv_b[i];
    if (i < 2 * Ff) {  // layers 0,1 have BN
        float s = gamma[i] * rsqrtf(var[i] + 1e-5f);
        sc[i] = s;
        sh[i] = (b - mean[i]) * s + beta[i];
    } else {           // layer 2: no BN
        sc[i] = 1.0f;
        sh[i] = b;
    }
}

// ---------------- CSR build ----------------
__global__ void count_edges_k(const int* __restrict__ dst, int* __restrict__ deg)
{
    int e = blockIdx.x * 256 + threadIdx.x;
    if (e < Ee) atomicAdd(&deg[dst[e]], 1);
}

__global__ void chunk_sum_k(const int* __restrict__ deg, int* __restrict__ csum)
{
    int t = blockIdx.x * 256 + threadIdx.x;
    if (t >= NCH) return;
    int i0 = t * CH, i1 = min(i0 + CH, Nn);
    int s = 0;
    for (int i = i0; i < i1; ++i) s += deg[i];
    csum[t] = s;
}

__global__ void scan_chunks_k(const int* __restrict__ csum, int* __restrict__ coff)
{
    __shared__ int tot[256];
    int t = threadIdx.x;
    int v[8]; int s = 0;
    #pragma unroll
    for (int j = 0; j < 8; ++j) { v[j] = csum[t * 8 + j]; s += v[j]; }
    tot[t] = s;
    __syncthreads();
    for (int d = 1; d < 256; d <<= 1) {
        int x = (t >= d) ? tot[t - d] : 0;
        __syncthreads();
        tot[t] += x;
        __syncthreads();
    }
    int base = tot[t] - s;  // exclusive prefix
    #pragma unroll
    for (int j = 0; j < 8; ++j) { coff[t * 8 + j] = base; base += v[j]; }
}

__global__ void write_offsets_k(const int* __restrict__ deg, const int* __restrict__ coff,
                                int* __restrict__ off, float* __restrict__ dinv)
{
    int t = blockIdx.x * 256 + threadIdx.x;
    if (t >= NCH) return;
    int i0 = t * CH, i1 = min(i0 + CH, Nn);
    int run = coff[t];
    for (int i = i0; i < i1; ++i) {
        off[i] = run;
        int d = deg[i];
        run += d;
        dinv[i] = rsqrtf((float)d + 1.0f);  // +1 self loop
    }
    if (t == 0) off[Nn] = Ee;
}

__global__ void fill_csr_k(const int* __restrict__ src, const int* __restrict__ dst,
                           const int* __restrict__ off, int* __restrict__ cur,
                           int* __restrict__ csrc)
{
    int e = blockIdx.x * 256 + threadIdx.x;
    if (e < Ee) {
        int d = dst[e];
        int p = off[d] + atomicAdd(&cur[d], 1);
        csrc[p] = src[e];
    }
}

// ---------------- GEMM v2: Y[r] = (A[r] @ W) * dinv[r] ----------------
// No LDS. Wave-uniform column block -> W reads become s_load (scalar cache),
// consumed as the SGPR operand of v_fma. A read per-lane from global as
// float4 along k (contiguous). 256 thr = 4 waves; wave w owns cols w*32..+31;
// lane owns rows {blk*128+lane, +64}. acc = 2x32 VGPRs. Pure VALU-bound.
__global__ __launch_bounds__(256) void gemm_scale_k(
    const float* __restrict__ A, const float* __restrict__ W,
    const float* __restrict__ dinv, float* __restrict__ Y, int n)
{
    const int lane = threadIdx.x & 63;
    const int wv   = threadIdx.x >> 6;                       // 0..3
    const int colBase = __builtin_amdgcn_readfirstlane(wv) * 32;   // SGPR-uniform
    const int r0 = blockIdx.x * 128 + lane;
    const int r1 = r0 + 64;
    const float* a0p = A + (size_t)min(r0, n - 1) * Ff;
    const float* a1p = A + (size_t)min(r1, n - 1) * Ff;
    const float* Wp  = W + colBase;

    float acc0[32], acc1[32];
    #pragma unroll
    for (int c = 0; c < 32; ++c) { acc0[c] = 0.f; acc1[c] = 0.f; }

    #pragma unroll 2
    for (int k4 = 0; k4 < 32; ++k4) {
        const float4 a0 = *(const float4*)(a0p + k4 * 4);
        const float4 a1 = *(const float4*)(a1p + k4 * 4);
        #pragma unroll
        for (int kk = 0; kk < 4; ++kk) {
            const float* wr = Wp + (k4 * 4 + kk) * Ff;       // wave-uniform
            const float av0 = (&a0.x)[kk];
            const float av1 = (&a1.x)[kk];
            #pragma unroll
            for (int c = 0; c < 32; ++c) {
                const float wvv = wr[c];
                acc0[c] = fmaf(av0, wvv, acc0[c]);
                acc1[c] = fmaf(av1, wvv, acc1[c]);
            }
        }
    }

    if (r0 < n) {
        const float di = dinv[r0];
        float* yp = Y + (size_t)r0 * Ff + colBase;
        #pragma unroll
        for (int c = 0; c < 32; c += 4)
            *(float4*)(yp + c) = make_float4(acc0[c] * di, acc0[c + 1] * di,
                                             acc0[c + 2] * di, acc0[c + 3] * di);
    }
    if (r1 < n) {
        const float di = dinv[r1];
        float* yp = Y + (size_t)r1 * Ff + colBase;
        #pragma unroll
        for (int c = 0; c < 32; c += 4)
            *(float4*)(yp + c) = make_float4(acc1[c] * di, acc1[c + 1] * di,
                                             acc1[c + 2] * di, acc1[c + 3] * di);
    }
}

// ---------------- aggregation v2: one wave per node, 2 edges/instr ----------------
// Lane: half = lane>>5 (even/odd edge), fl = lane&31 (float4 feature slot).
// Each global_load_dwordx4 covers 2 full rows across the wave (1024 B).
// H[i] = act( dinv[i] * (sum_in Y[src] + Y[i]) * sc + sh )
__global__ __launch_bounds__(256) void aggregate_k(
    const float* __restrict__ Y, const int* __restrict__ off,
    const int* __restrict__ srcs, const float* __restrict__ dinv,
    const float* __restrict__ sc, const float* __restrict__ sh,
    float* __restrict__ H, int dorelu, int n)
{
    const int wid  = threadIdx.x >> 6;
    const int lane = threadIdx.x & 63;
    const int node = blockIdx.x * 4 + wid;
    if (node >= n) return;
    const int beg = off[node], end = off[node + 1];
    const int half = lane >> 5;
    const int fl   = lane & 31;
    const float4* Y4 = (const float4*)Y;

    float ax = 0.f, ay = 0.f, az = 0.f, aw = 0.f;
    float bx = 0.f, by = 0.f, bz = 0.f, bw = 0.f;
    if (half == 0) {  // self contribution, counted once
        float4 s4 = Y4[(size_t)node * 32 + fl];
        ax = s4.x; ay = s4.y; az = s4.z; aw = s4.w;
    }

    for (int e = beg; e < end; e += 64) {
        const int nb = min(64, end - e);
        int sidx = (lane < nb) ? srcs[e + lane] : 0;
        int j = 0;
        for (; j + 8 <= nb; j += 8) {
            int s0 = __shfl(sidx, j + 0 + half);
            int s1 = __shfl(sidx, j + 2 + half);
            int s2 = __shfl(sidx, j + 4 + half);
            int s3 = __shfl(sidx, j + 6 + half);
            float4 v0 = Y4[(size_t)s0 * 32 + fl];
            float4 v1 = Y4[(size_t)s1 * 32 + fl];
            float4 v2 = Y4[(size_t)s2 * 32 + fl];
            float4 v3 = Y4[(size_t)s3 * 32 + fl];
            ax += v0.x; ay += v0.y; az += v0.z; aw += v0.w;
            bx += v1.x; by += v1.y; bz += v1.z; bw += v1.w;
            ax += v2.x; ay += v2.y; az += v2.z; aw += v2.w;
            bx += v3.x; by += v3.y; bz += v3.z; bw += v3.w;
        }
        for (; j < nb; j += 2) {
            const int eo = j + half;
            int s = __shfl(sidx, (eo < nb) ? eo : (nb - 1));  // shfl wave-wide
            if (eo < nb) {
                float4 v = Y4[(size_t)s * 32 + fl];
                ax += v.x; ay += v.y; az += v.z; aw += v.w;
            }
        }
    }
    ax += bx; ay += by; az += bz; aw += bw;
    // combine the two half-wave partial sums (both halves active here)
    float rx = ax + __shfl_xor(ax, 32);
    float ry = ay + __shfl_xor(ay, 32);
    float rz = az + __shfl_xor(az, 32);
    float rw = aw + __shfl_xor(aw, 32);

    if (half == 0) {
        const float di = dinv[node];
        const float4 scv = ((const float4*)sc)[fl];
        const float4 shv = ((const float4*)sh)[fl];
        float4 o;
        o.x = rx * di * scv.x + shv.x;
        o.y = ry * di * scv.y + shv.y;
        o.z = rz * di * scv.z + shv.z;
        o.w = rw * di * scv.w + shv.w;
        if (dorelu) {
            o.x = fmaxf(o.x, 0.f); o.y = fmaxf(o.y, 0.f);
            o.z = fmaxf(o.z, 0.f); o.w = fmaxf(o.w, 0.f);
        }
        ((float4*)H)[(size_t)node * 32 + fl] = o;
    }
}

// ---------------- mean-pool (batch sorted -> binary search) + linear ----------------
__global__ __launch_bounds__(128) void pool_linear_k(
    const float* __restrict__ H, const int* __restrict__ batch,
    const float* __restrict__ lw, const float* __restrict__ lb,
    float* __restrict__ out)
{
    int g = blockIdx.x, f = threadIdx.x;
    int lo = 0, hi = Nn;
    while (lo < hi) { int m = (lo + hi) >> 1; if (batch[m] < g) lo = m + 1; else hi = m; }
    int start = lo;
    hi = Nn;
    while (lo < hi) { int m = (lo + hi) >> 1; if (batch[m] < g + 1) lo = m + 1; else hi = m; }
    int end = lo;

    float a0 = 0.f, a1 = 0.f, a2 = 0.f, a3 = 0.f;
    int i = start;
    for (; i + 4 <= end; i += 4) {
        a0 += H[(size_t)(i + 0) * Ff + f];
        a1 += H[(size_t)(i + 1) * Ff + f];
        a2 += H[(size_t)(i + 2) * Ff + f];
        a3 += H[(size_t)(i + 3) * Ff + f];
    }
    for (; i < end; ++i) a0 += H[(size_t)i * Ff + f];
    int cnt = end - start;
    __shared__ float pooled[Ff];
    pooled[f] = ((a0 + a1) + (a2 + a3)) / (float)max(cnt, 1);
    __syncthreads();
    if (f < Cc) {
        float o = lb[f];
        #pragma unroll 8
        for (int k = 0; k < Ff; ++k) o += pooled[k] * lw[k * Cc + f];
        out[g * Cc + f] = o;
    }
}

// ---------------- launch ----------------
extern "C" void kernel_launch(void* const* d_in, const int* in_sizes, int n_in,
                              void* d_out, int out_size, void* d_ws, size_t ws_size,
                              hipStream_t stream)
{
    const float* x      = (const float*)d_in[0];
    const int*   ei     = (const int*)d_in[1];   // [2,E]: src=ei[0:E), dst=ei[E:2E)
    const int*   batch  = (const int*)d_in[2];
    const float* conv_w = (const float*)d_in[3]; // [3,128,128]
    const float* conv_b = (const float*)d_in[4];
    const float* gamma  = (const float*)d_in[5];
    const float* beta   = (const float*)d_in[6];
    const float* mean   = (const float*)d_in[7];
    const float* var    = (const float*)d_in[8];
    const float* lw     = (const float*)d_in[9];
    const float* lb     = (const float*)d_in[10];
    float* out = (float*)d_out;

    const int* srcp = ei;
    const int* dstp = ei + Ee;

    // workspace layout
    float* h    = (float*)d_ws;            // N*F
    float* y    = h + (size_t)Nn * Ff;     // N*F
    float* dinv = y + (size_t)Nn * Ff;     // N
    float* sc   = dinv + Nn;               // 3*F
    float* sh   = sc + 3 * Ff;             // 3*F
    int*   deg  = (int*)(sh + 3 * Ff);     // N
    int*   cur  = deg + Nn;                // N  (adjacent to deg: one memset)
    int*   off  = cur + Nn;                // N+1
    int*   csrc = off + (Nn + 1);          // E
    int*   csum = csrc + Ee;               // NCH
    int*   coff = csum + NCH;              // NCH

    hipMemsetAsync(deg, 0, 2 * (size_t)Nn * sizeof(int), stream);

    prep_scales_k<<<2, 256, 0, stream>>>(conv_b, gamma, beta, mean, var, sc, sh);
    count_edges_k<<<Ee / 256, 256, 0, stream>>>(dstp, deg);
    chunk_sum_k<<<NCH / 256, 256, 0, stream>>>(deg, csum);
    scan_chunks_k<<<1, 256, 0, stream>>>(csum, coff);
    write_offsets_k<<<NCH / 256, 256, 0, stream>>>(deg, coff, off, dinv);
    fill_csr_k<<<Ee / 256, 256, 0, stream>>>(srcp, dstp, off, cur, csrc);

    const int gemm_grid = (Nn + 127) / 128;
    const int agg_grid  = (Nn + 3) / 4;
    for (int l = 0; l < 3; ++l) {
        const float* in = (l == 0) ? x : h;
        gemm_scale_k<<<gemm_grid, 256, 0, stream>>>(in, conv_w + (size_t)l * Ff * Ff,
                                                    dinv, y, Nn);
        aggregate_k<<<agg_grid, 256, 0, stream>>>(y, off, csrc, dinv,
                                                  sc + l * Ff, sh + l * Ff,
                                                  h, (l < 2) ? 1 : 0, Nn);
    }
    pool_linear_k<<<Gg, 128, 0, stream>>>(h, batch, lw, lb, out);
}